// Round 3
// baseline (402.645 us; speedup 1.0000x reference)
//
#include <hip/hip_runtime.h>
#include <stdint.h>

#define N_NODES 4096
#define F_DIM   64
#define LRELU_ALPHA 0.2f

typedef _Float16 f16;
typedef __attribute__((ext_vector_type(8))) _Float16 half8;  // MFMA f16 A/B frag (4 VGPRs)
typedef __attribute__((ext_vector_type(4))) float f32x4;     // MFMA C/D frag

// ---------------------------------------------------------------------------
// Kernel 1: PREP ONLY. 1024 blocks x 256. (pack role now lives inside
// gat_attn as a wave-private LDS prologue -- bits never touch HBM.)
// Wh = h@W; ei=Wh·a1, ej=Wh·a2; whB in MFMA B-fragment order:
//   whB[((b*128+jc)*4+fc)*512 + (q*16+m)*8 + x] = Wh[j=jc*32+q*8+x][f=fc*16+m]
// blockmax[pid] = max ej over the block's 16 rows.
// ---------------------------------------------------------------------------
__global__ __launch_bounds__(256) void gat_prep(
    const float* __restrict__ h, const float* __restrict__ W,
    const float* __restrict__ a,
    float* __restrict__ ei, float* __restrict__ ej,
    f16* __restrict__ whB, float* __restrict__ blockmax)
{
  __shared__ float sh_h[4][F_DIM];
  __shared__ f16 tile[F_DIM][16];   // [f][loc]
  __shared__ float wmax[4];
  const int t = threadIdx.x, w = t >> 6, lane = t & 63;
  const int pid = blockIdx.x;
  const int n0 = pid * 16;              // global row base (0..16383)
  const int b  = n0 >> 12;
  const int nl0 = n0 & (N_NODES - 1);   // row base within batch

  float wcol[F_DIM];
#pragma unroll
  for (int k = 0; k < F_DIM; ++k) wcol[k] = W[k * F_DIM + lane];
  const float a1 = a[lane], a2 = a[F_DIM + lane];

  float runmax = -3e38f;
  for (int r = 0; r < 4; ++r) {
    const int loc = w * 4 + r;
    const int n = n0 + loc;
    const float hv = h[(size_t)n * F_DIM + lane];
    sh_h[w][lane] = hv;                       // same-wave LDS write->read
    float wh = 0.f;
#pragma unroll
    for (int k = 0; k < F_DIM; k += 4) {
      const float4 hb = *(const float4*)(&sh_h[w][k]);
      wh = fmaf(hb.x, wcol[k + 0], wh);
      wh = fmaf(hb.y, wcol[k + 1], wh);
      wh = fmaf(hb.z, wcol[k + 2], wh);
      wh = fmaf(hb.w, wcol[k + 3], wh);
    }
    float s1 = wh * a1, s2 = wh * a2;
#pragma unroll
    for (int off = 32; off; off >>= 1) {
      s1 += __shfl_xor(s1, off);
      s2 += __shfl_xor(s2, off);
    }
    if (lane == 0) { ei[n] = s1; ej[n] = s2; }
    runmax = fmaxf(runmax, s2);               // s2 identical on all lanes
    tile[lane][loc] = (f16)wh;                // f = lane
  }
  if (lane == 0) wmax[w] = runmax;
  __syncthreads();

  // B-fragment-order store (coalesced 8-B): jc/q0 fixed per block.
  {
    const int jc = nl0 >> 5;
    const int q0 = (nl0 >> 3) & 3;            // in {0, 2}
    const int fc = t >> 6;
    const int r6 = t & 63;
    const int qp = r6 >> 5;                   // q' in {0,1}
    const int m  = (r6 >> 1) & 15;
    const int xh = (t & 1) * 4;
    const int loc = qp * 8 + xh;              // source loc (+0..3)
    f16* dst = whB + (((size_t)(b * 128 + jc)) * 4 + fc) * 512
                   + ((q0 + qp) * 16 + m) * 8 + xh;
    *(uint2*)dst = *(const uint2*)(&tile[fc * 16 + m][loc]);
  }
  if (t == 0)
    blockmax[pid] =
        fmaxf(fmaxf(wmax[0], wmax[1]), fmaxf(wmax[2], wmax[3]));
}

// ---------------------------------------------------------------------------
// Kernel 2: FULLY FUSED pack + attention + PV (f16 MFMA) + ELU.
// Block = 32 rows (two 16-row i-tiles), 512 thr = 8 waves, grid 512 (2/CU).
//
// PACK PROLOGUE (new): wave w ballot-packs ITS OWN j-window [w*512,(w+1)*512)
// of the block's 32 adj rows into LDS -- wave-private produce/consume, so NO
// __syncthreads between pack and attn; adj stream (268 MB, int4 loads = 16B/
// lane) overlaps attn compute across waves. Bits alias the first 2 KB of the
// wave's own num_lds slice (LDS stays 65 KB -> 2 blocks/CU); a barrier after
// the main loop orders last bits read vs num_lds overwrite.
// Bit layout (from int4 ballots): per row, per 256-j window, 4 qwords q[c];
// bit L of q[c] <-> j = W*256 + 4L + c. Consumer: j = jc*32 + quad*8 + x ->
// wi = jc>>3, c = x&3, L = (jc&7)*8 + 2*quad + (x>>2).
//
// Spill discipline (round-1 lesson): flat unroll(1) j8 loop, one iteration's
// loads in flight; prologue v[8] int4 regs are transient. ~110 VGPR target.
// Range control per tile: bnd = leaky(ei + maxej_batch) >= row max (leaky
// monotone); arg = max(ej+c1, fma(0.2,ej,c2)) <= 0 -> p in (0,1], f16-safe;
// shift cancels in num/den.
// A-frag: A[m=lane&15][k=quad*8+x]; B-frag: B[k=quad*8+x][n=m];
// C/D: row=quad*4+reg, col=lane&15 (HW-verified m89/m91).
// ---------------------------------------------------------------------------
__global__ __launch_bounds__(512, 4) void gat_attn(
    const int* __restrict__ adj, const float* __restrict__ ei,
    const float* __restrict__ ej, const f16* __restrict__ whB,
    const float* __restrict__ blockmax, float* __restrict__ out)
{
  __shared__ float num_lds[8][32][F_DIM];   // 64 KB; per-wave first 2 KB doubles as bits
  __shared__ float den_lds[8][32];          // 1 KB

  const int t = threadIdx.x, w = t >> 6, lane = t & 63;
  const int quad = lane >> 4, m = lane & 15;
  const int kq = quad * 8;
  const int b  = blockIdx.x >> 7;            // 128 32-row chunks per batch
  const int i0 = (blockIdx.x & 127) * 32;
  const int rowg0 = b * N_NODES + i0 + m;        // tile 0 row (this lane)
  const int rowg1 = rowg0 + 16;                  // tile 1 row

  // wave-private bits store: [row][wi][c] = row*8 + wi*4 + c (uint64s)
  uint64_t* mybits = (uint64_t*)(&num_lds[w][0][0]);

  // ---- pack prologue: this wave's 512-j window for all 32 block rows ----
  {
    const int* base = adj + ((size_t)(b * N_NODES + i0)) * N_NODES + w * 512;
#pragma unroll 1
    for (int b8 = 0; b8 < 8; ++b8) {        // 8 batches: 4 rows x 2 windows
      int4 v[8];
#pragma unroll
      for (int s = 0; s < 8; ++s) {
        const int r = b8 * 4 + (s >> 1), wi = s & 1;
        v[s] = *((const int4*)(base + (size_t)r * N_NODES + wi * 256) + lane);
      }
#pragma unroll
      for (int s = 0; s < 8; ++s) {
        const int r = b8 * 4 + (s >> 1), wi = s & 1;
        const uint64_t q0 = __ballot(v[s].x > 0);
        const uint64_t q1 = __ballot(v[s].y > 0);
        const uint64_t q2 = __ballot(v[s].z > 0);
        const uint64_t q3 = __ballot(v[s].w > 0);
        if (lane == 0) {
          uint64_t* q = mybits + r * 8 + wi * 4;
          q[0] = q0; q[1] = q1; q[2] = q2; q[3] = q3;
        }
      }
    }
  }
  // no barrier needed: bits are wave-private (same wave produces & consumes)

  // per-batch max(ej): reduce 256 per-block maxima (L2-hot)
  float maxej;
  {
    const float4 v = *(const float4*)(blockmax + b * 256 + lane * 4);
    maxej = fmaxf(fmaxf(v.x, v.y), fmaxf(v.z, v.w));
#pragma unroll
    for (int off = 32; off; off >>= 1)
      maxej = fmaxf(maxej, __shfl_xor(maxej, off));
  }

  const float ei0 = ei[rowg0], ei1 = ei[rowg1];
  float bnd0 = ei0 + maxej;
  bnd0 = fmaxf(bnd0, LRELU_ALPHA * bnd0);
  float bnd1 = ei1 + maxej;
  bnd1 = fmaxf(bnd1, LRELU_ALPHA * bnd1);
  const float c10 = ei0 - bnd0, c20 = LRELU_ALPHA * ei0 - bnd0;
  const float c11 = ei1 - bnd1, c21 = LRELU_ALPHA * ei1 - bnd1;

  const float* ejb = ej + b * N_NODES + w * 512;       // this wave's j window
  const f16* whw = whB + ((size_t)(b * 128 + w * 16)) * 2048 + lane * 8;

  f32x4 acc0[4] = {{0.f,0.f,0.f,0.f},{0.f,0.f,0.f,0.f},
                   {0.f,0.f,0.f,0.f},{0.f,0.f,0.f,0.f}};
  f32x4 acc1[4] = {{0.f,0.f,0.f,0.f},{0.f,0.f,0.f,0.f},
                   {0.f,0.f,0.f,0.f},{0.f,0.f,0.f,0.f}};
  float dA0 = 0.f, dB0 = 0.f, dA1 = 0.f, dB1 = 0.f;

#pragma unroll 1
  for (int wi = 0; wi < 2; ++wi) {
    // stage this window's bits for both tile rows (held 8 iterations)
    uint64_t q0[4], q1[4];
#pragma unroll
    for (int c = 0; c < 4; ++c) {
      q0[c] = mybits[m * 8 + wi * 4 + c];
      q1[c] = mybits[(m + 16) * 8 + wi * 4 + c];
    }

#pragma unroll 1
    for (int j8 = 0; j8 < 8; ++j8) {
      const int jc = wi * 8 + j8;
      const int Lb = j8 * 8 + 2 * quad;      // + (x>>2) selects the bit

      float ejA[8];
      *(float4*)(&ejA[0]) = *(const float4*)(ejb + jc * 32 + kq);
      *(float4*)(&ejA[4]) = *(const float4*)(ejb + jc * 32 + kq + 4);

      const f16* wjc = whw + (size_t)jc * 2048;
      half8 bf[4];
#pragma unroll
      for (int fc = 0; fc < 4; ++fc)
        bf[fc] = *(const half8*)(wjc + fc * 512);

      half8 pa0, pa1;
#pragma unroll
      for (int x = 0; x < 8; ++x) {
        const float e = ejA[x];
        const float g0 = fmaxf(e + c10, fmaf(LRELU_ALPHA, e, c20));
        const float g1 = fmaxf(e + c11, fmaf(LRELU_ALPHA, e, c21));
        const uint32_t bit0 = (uint32_t)(q0[x & 3] >> (Lb + (x >> 2))) & 1u;
        const uint32_t bit1 = (uint32_t)(q1[x & 3] >> (Lb + (x >> 2))) & 1u;
        const float p0 = bit0 ? __expf(g0) : 0.f;
        const float p1 = bit1 ? __expf(g1) : 0.f;
        pa0[x] = (f16)p0;
        pa1[x] = (f16)p1;
        if (x & 1) { dB0 += p0; dB1 += p1; }   // two chains: half the depth
        else       { dA0 += p0; dA1 += p1; }
      }

#pragma unroll
      for (int fc = 0; fc < 4; ++fc) {
        acc0[fc] = __builtin_amdgcn_mfma_f32_16x16x32_f16(pa0, bf[fc], acc0[fc], 0, 0, 0);
        acc1[fc] = __builtin_amdgcn_mfma_f32_16x16x32_f16(pa1, bf[fc], acc1[fc], 0, 0, 0);
      }
    }
  }

  // order: every wave done reading its bits before num_lds gets overwritten
  __syncthreads();

  float den0 = dA0 + dB0, den1 = dA1 + dB1;
  // den: lanes sharing a row (same lane&15) live 16 apart
  den0 += __shfl_xor(den0, 16);
  den0 += __shfl_xor(den0, 32);
  den1 += __shfl_xor(den1, 16);
  den1 += __shfl_xor(den1, 32);
  if (lane < 16) {
    den_lds[w][lane] = den0;
    den_lds[w][lane + 16] = den1;
  }

#pragma unroll
  for (int fc = 0; fc < 4; ++fc)
#pragma unroll
    for (int rg = 0; rg < 4; ++rg) {
      num_lds[w][quad * 4 + rg][fc * 16 + m] = acc0[fc][rg];
      num_lds[w][16 + quad * 4 + rg][fc * 16 + m] = acc1[fc][rg];
    }
  __syncthreads();

  // merge 8 wave-partials, divide, ELU, coalesced store (2048 outs, 512 thr)
#pragma unroll
  for (int k = 0; k < 4; ++k) {
    const int idx = k * 512 + t;
    const int il = idx >> 6, f = idx & 63;
    float num = 0.f, d = 0.f;
#pragma unroll
    for (int ww = 0; ww < 8; ++ww) {
      num += num_lds[ww][il][f];
      d   += den_lds[ww][il];
    }
    float v = (d > 0.f) ? (num / d) : 0.f;
    v = (v > 0.f) ? v : expm1f(v);
    out[((size_t)(b * N_NODES + i0 + il)) * F_DIM + f] = v;
  }
}

extern "C" void kernel_launch(void* const* d_in, const int* in_sizes, int n_in,
                              void* d_out, int out_size, void* d_ws, size_t ws_size,
                              hipStream_t stream) {
  const float* h   = (const float*)d_in[0];
  const int*   adj = (const int*)d_in[1];
  const float* W   = (const float*)d_in[2];
  const float* a   = (const float*)d_in[3];
  float* out = (float*)d_out;

  char* ws = (char*)d_ws;
  // Workspace (~2.2 MB, bits buffer eliminated):
  // [0,       +64 KB)  ei
  // [65536,   +64 KB)  ej
  // [131072,  +4 KB)   blockmax (1024 floats)
  // [135168,  +2 MB)   whB (B-fragment-order Wh, 2M f16 exactly)
  float*    ei       = (float*)ws;
  float*    ej       = (float*)(ws + 65536);
  float*    blockmax = (float*)(ws + 131072);
  f16*      whB      = (f16*)(ws + 135168);

  hipLaunchKernelGGL(gat_prep, dim3(1024), dim3(256), 0, stream,
                     h, W, a, ei, ej, whB, blockmax);
  hipLaunchKernelGGL(gat_attn, dim3(512), dim3(512), 0, stream,
                     adj, ei, ej, whB, blockmax, out);
}

// Round 5
// 393.350 us; speedup vs baseline: 1.0236x; 1.0236x over previous
//
#include <hip/hip_runtime.h>
#include <stdint.h>

#define N_NODES 4096
#define F_DIM   64
#define LRELU_ALPHA 0.2f

typedef _Float16 f16;
typedef __attribute__((ext_vector_type(8))) _Float16 half8;  // MFMA f16 A/B frag (4 VGPRs)
typedef __attribute__((ext_vector_type(4))) float f32x4;     // MFMA C/D frag

// ---------------------------------------------------------------------------
// Kernel 0+1 FUSED, roles INTERLEAVED 1:5 (round-2 structure, best measured).
// blockIdx%5==0 -> prep (1024 of 5120), else pack (4096 blocks x 4 rows).
// prep's VALU/LDS work rides under pack's HBM stream.
// pack: bits[row*128 + d] bit (j&31) = adj[row][j] > 0. 16-deep dword loads,
//       256B/wave-instr, batch loop unroll(1) caps in-flight (spill lesson).
// prep: Wh = h@W; ei=Wh·a1, ej=Wh·a2; whB in MFMA B-fragment order:
//   whB[((b*128+jc)*4+fc)*512 + (q*16+m)*8 + x] = Wh[j=jc*32+q*8+x][f=fc*16+m]
//   blockmax[pid] = max ej over the prep block's 16 rows.
// ---------------------------------------------------------------------------
__global__ __launch_bounds__(256) void gat_pp(
    const float* __restrict__ h, const float* __restrict__ W,
    const float* __restrict__ a, const int* __restrict__ adj,
    float* __restrict__ ei, float* __restrict__ ej,
    f16* __restrict__ whB, float* __restrict__ blockmax,
    uint32_t* __restrict__ bits)
{
  __shared__ float sh_h[4][F_DIM];
  __shared__ f16 tile[F_DIM][16];   // [f][loc]
  __shared__ float wmax[4];
  const int t = threadIdx.x, w = t >> 6, lane = t & 63;
  const int bid = blockIdx.x;
  const int pid = bid / 5;

  if (bid % 5 != 0) {
    // ---------------- pack role: 4 rows/block, 1 row/wave ----------------
    const int pk = bid - 1 - pid;                 // 0..4095
    const int row = pk * 4 + w;                   // this wave's adj row
    const int* rowp = adj + (size_t)row * N_NODES + lane;
    uint64_t* dst = (uint64_t*)(bits + (size_t)row * 128);

#pragma unroll 1
    for (int bch = 0; bch < 4; ++bch) {           // 4 batches of 1024 j
      int v[16];
#pragma unroll
      for (int s = 0; s < 16; ++s)
        v[s] = rowp[(bch * 16 + s) * 64];         // 16 loads in flight
#pragma unroll
      for (int s = 0; s < 16; ++s) {
        const unsigned long long m = __ballot(v[s] > 0);
        if (lane == 0) dst[bch * 16 + s] = m;
      }
    }
    return;
  }

  // ---------------- prep role ----------------
  const int n0 = pid * 16;              // global row base (0..16383)
  const int b  = n0 >> 12;
  const int nl0 = n0 & (N_NODES - 1);   // row base within batch

  float wcol[F_DIM];
#pragma unroll
  for (int k = 0; k < F_DIM; ++k) wcol[k] = W[k * F_DIM + lane];
  const float a1 = a[lane], a2 = a[F_DIM + lane];

  float runmax = -3e38f;
  for (int r = 0; r < 4; ++r) {
    const int loc = w * 4 + r;
    const int n = n0 + loc;
    const float hv = h[(size_t)n * F_DIM + lane];
    sh_h[w][lane] = hv;                       // same-wave LDS write->read
    float wh = 0.f;
#pragma unroll
    for (int k = 0; k < F_DIM; k += 4) {
      const float4 hb = *(const float4*)(&sh_h[w][k]);
      wh = fmaf(hb.x, wcol[k + 0], wh);
      wh = fmaf(hb.y, wcol[k + 1], wh);
      wh = fmaf(hb.z, wcol[k + 2], wh);
      wh = fmaf(hb.w, wcol[k + 3], wh);
    }
    float s1 = wh * a1, s2 = wh * a2;
#pragma unroll
    for (int off = 32; off; off >>= 1) {
      s1 += __shfl_xor(s1, off);
      s2 += __shfl_xor(s2, off);
    }
    if (lane == 0) { ei[n] = s1; ej[n] = s2; }
    runmax = fmaxf(runmax, s2);               // s2 identical on all lanes
    tile[lane][loc] = (f16)wh;                // f = lane
  }
  if (lane == 0) wmax[w] = runmax;
  __syncthreads();

  // B-fragment-order store (coalesced 8-B): jc/q0 fixed per block.
  {
    const int jc = nl0 >> 5;
    const int q0 = (nl0 >> 3) & 3;            // in {0, 2}
    const int fc = t >> 6;
    const int r6 = t & 63;
    const int qp = r6 >> 5;                   // q' in {0,1}
    const int m  = (r6 >> 1) & 15;
    const int xh = (t & 1) * 4;
    const int loc = qp * 8 + xh;              // source loc (+0..3)
    f16* dst = whB + (((size_t)(b * 128 + jc)) * 4 + fc) * 512
                   + ((q0 + qp) * 16 + m) * 8 + xh;
    *(uint2*)dst = *(const uint2*)(&tile[fc * 16 + m][loc]);
  }
  if (t == 0)
    blockmax[pid] =
        fmaxf(fmaxf(wmax[0], wmax[1]), fmaxf(wmax[2], wmax[3]));
}

// ---------------------------------------------------------------------------
// Kernel 2: attention + PV (f16 MFMA) + ELU. Round-2 base, two changes:
// (a) __launch_bounds__(512, 2): round-1 evidence says (512,4)'s 128-reg cap
//     (incl. 32-reg acc) drives the allocator into scratch; LDS (65KB) still
//     pins occupancy at 2 blocks/CU, so the cap bought nothing.
// (b) depth-2 software pipeline: next jc's {2 bit-dwords, ejA 8 f32, bf 4x
//     half8} prefetched into regs during current jc's exp+MFMA (~500 cyc of
//     slack covers the L2 gather latency). Branch-free: last iter re-reads
//     jc=15 harmlessly. +26 live VGPR over ~100 base -> ~130, fits (512,2).
// Range control per tile: bnd = leaky(ei + maxej_batch) >= row max (leaky
// monotone); arg = max(ej+c1, fma(0.2,ej,c2)) <= 0 -> p in (0,1], f16-safe;
// shift cancels in num/den.
// A-frag: A[m=lane&15][k=quad*8+x]; B-frag: B[k=quad*8+x][n=m];
// C/D: row=quad*4+reg, col=lane&15 (HW-verified m89/m91).
// ---------------------------------------------------------------------------
__global__ __launch_bounds__(512, 2) void gat_attn(
    const uint32_t* __restrict__ bits, const float* __restrict__ ei,
    const float* __restrict__ ej, const f16* __restrict__ whB,
    const float* __restrict__ blockmax, float* __restrict__ out)
{
  __shared__ float num_lds[8][32][F_DIM];   // 64 KB
  __shared__ float den_lds[8][32];          // 1 KB

  const int t = threadIdx.x, w = t >> 6, lane = t & 63;
  const int quad = lane >> 4, m = lane & 15;
  const int kq = quad * 8;
  const int b  = blockIdx.x >> 7;            // 128 32-row chunks per batch
  const int i0 = (blockIdx.x & 127) * 32;
  const int rowg0 = b * N_NODES + i0 + m;        // tile 0 row (this lane)
  const int rowg1 = rowg0 + 16;                  // tile 1 row

  // per-batch max(ej): reduce 256 per-block maxima (L2-hot)
  float maxej;
  {
    const float4 v = *(const float4*)(blockmax + b * 256 + lane * 4);
    maxej = fmaxf(fmaxf(v.x, v.y), fmaxf(v.z, v.w));
#pragma unroll
    for (int off = 32; off; off >>= 1)
      maxej = fmaxf(maxej, __shfl_xor(maxej, off));
  }

  const float ei0 = ei[rowg0], ei1 = ei[rowg1];
  float bnd0 = ei0 + maxej;
  bnd0 = fmaxf(bnd0, LRELU_ALPHA * bnd0);
  float bnd1 = ei1 + maxej;
  bnd1 = fmaxf(bnd1, LRELU_ALPHA * bnd1);
  const float c10 = ei0 - bnd0, c20 = LRELU_ALPHA * ei0 - bnd0;
  const float c11 = ei1 - bnd1, c21 = LRELU_ALPHA * ei1 - bnd1;

  const float* ejb = ej + b * N_NODES + w * 512;       // this wave's j window
  const uint32_t* bitrow0 = bits + (size_t)rowg0 * 128 + w * 16;
  const uint32_t* bitrow1 = bits + (size_t)rowg1 * 128 + w * 16;
  const f16* whw = whB + ((size_t)(b * 128 + w * 16)) * 2048 + lane * 8;

  f32x4 acc0[4] = {{0.f,0.f,0.f,0.f},{0.f,0.f,0.f,0.f},
                   {0.f,0.f,0.f,0.f},{0.f,0.f,0.f,0.f}};
  f32x4 acc1[4] = {{0.f,0.f,0.f,0.f},{0.f,0.f,0.f,0.f},
                   {0.f,0.f,0.f,0.f},{0.f,0.f,0.f,0.f}};
  float dA0 = 0.f, dB0 = 0.f, dA1 = 0.f, dB1 = 0.f;

  // ---- prime the pipeline: jc = 0 ----
  uint32_t dw0 = bitrow0[0], dw1 = bitrow1[0];
  float4 ejL = *(const float4*)(ejb + kq);
  float4 ejH = *(const float4*)(ejb + kq + 4);
  half8 bf0 = *(const half8*)(whw + 0 * 512);
  half8 bf1 = *(const half8*)(whw + 1 * 512);
  half8 bf2 = *(const half8*)(whw + 2 * 512);
  half8 bf3 = *(const half8*)(whw + 3 * 512);

#pragma unroll 1
  for (int jc = 0; jc < 16; ++jc) {
    // ---- prefetch jc+1 (clamped; last iter re-reads 15 harmlessly) ----
    const int jn = (jc < 15) ? jc + 1 : 15;
    const uint32_t ndw0 = bitrow0[jn];
    const uint32_t ndw1 = bitrow1[jn];
    const float4 nejL = *(const float4*)(ejb + jn * 32 + kq);
    const float4 nejH = *(const float4*)(ejb + jn * 32 + kq + 4);
    const f16* wjn = whw + (size_t)jn * 2048;
    const half8 nbf0 = *(const half8*)(wjn + 0 * 512);
    const half8 nbf1 = *(const half8*)(wjn + 1 * 512);
    const half8 nbf2 = *(const half8*)(wjn + 2 * 512);
    const half8 nbf3 = *(const half8*)(wjn + 3 * 512);

    // ---- compute on current regs (covers prefetch latency) ----
    float ejA[8];
    *(float4*)(&ejA[0]) = ejL;
    *(float4*)(&ejA[4]) = ejH;

    half8 pa0, pa1;
#pragma unroll
    for (int x = 0; x < 8; ++x) {
      const float e = ejA[x];
      const float g0 = fmaxf(e + c10, fmaf(LRELU_ALPHA, e, c20));
      const float g1 = fmaxf(e + c11, fmaf(LRELU_ALPHA, e, c21));
      const float p0 = ((dw0 >> (kq + x)) & 1u) ? __expf(g0) : 0.f;
      const float p1 = ((dw1 >> (kq + x)) & 1u) ? __expf(g1) : 0.f;
      pa0[x] = (f16)p0;
      pa1[x] = (f16)p1;
      if (x & 1) { dB0 += p0; dB1 += p1; }   // two chains: half the depth
      else       { dA0 += p0; dA1 += p1; }
    }

    acc0[0] = __builtin_amdgcn_mfma_f32_16x16x32_f16(pa0, bf0, acc0[0], 0, 0, 0);
    acc1[0] = __builtin_amdgcn_mfma_f32_16x16x32_f16(pa1, bf0, acc1[0], 0, 0, 0);
    acc0[1] = __builtin_amdgcn_mfma_f32_16x16x32_f16(pa0, bf1, acc0[1], 0, 0, 0);
    acc1[1] = __builtin_amdgcn_mfma_f32_16x16x32_f16(pa1, bf1, acc1[1], 0, 0, 0);
    acc0[2] = __builtin_amdgcn_mfma_f32_16x16x32_f16(pa0, bf2, acc0[2], 0, 0, 0);
    acc1[2] = __builtin_amdgcn_mfma_f32_16x16x32_f16(pa1, bf2, acc1[2], 0, 0, 0);
    acc0[3] = __builtin_amdgcn_mfma_f32_16x16x32_f16(pa0, bf3, acc0[3], 0, 0, 0);
    acc1[3] = __builtin_amdgcn_mfma_f32_16x16x32_f16(pa1, bf3, acc1[3], 0, 0, 0);

    // ---- rotate pipeline regs ----
    dw0 = ndw0; dw1 = ndw1;
    ejL = nejL; ejH = nejH;
    bf0 = nbf0; bf1 = nbf1; bf2 = nbf2; bf3 = nbf3;
  }

  float den0 = dA0 + dB0, den1 = dA1 + dB1;
  // den: lanes sharing a row (same lane&15) live 16 apart
  den0 += __shfl_xor(den0, 16);
  den0 += __shfl_xor(den0, 32);
  den1 += __shfl_xor(den1, 16);
  den1 += __shfl_xor(den1, 32);
  if (lane < 16) {
    den_lds[w][lane] = den0;
    den_lds[w][lane + 16] = den1;
  }

#pragma unroll
  for (int fc = 0; fc < 4; ++fc)
#pragma unroll
    for (int rg = 0; rg < 4; ++rg) {
      num_lds[w][quad * 4 + rg][fc * 16 + m] = acc0[fc][rg];
      num_lds[w][16 + quad * 4 + rg][fc * 16 + m] = acc1[fc][rg];
    }
  __syncthreads();

  // merge 8 wave-partials, divide, ELU, coalesced store (2048 outs, 512 thr)
#pragma unroll
  for (int k = 0; k < 4; ++k) {
    const int idx = k * 512 + t;
    const int il = idx >> 6, f = idx & 63;
    float num = 0.f, d = 0.f;
#pragma unroll
    for (int ww = 0; ww < 8; ++ww) {
      num += num_lds[ww][il][f];
      d   += den_lds[ww][il];
    }
    float v = (d > 0.f) ? (num / d) : 0.f;
    v = (v > 0.f) ? v : expm1f(v);
    out[((size_t)(b * N_NODES + i0 + il)) * F_DIM + f] = v;
  }
}

extern "C" void kernel_launch(void* const* d_in, const int* in_sizes, int n_in,
                              void* d_out, int out_size, void* d_ws, size_t ws_size,
                              hipStream_t stream) {
  const float* h   = (const float*)d_in[0];
  const int*   adj = (const int*)d_in[1];
  const float* W   = (const float*)d_in[2];
  const float* a   = (const float*)d_in[3];
  float* out = (float*)d_out;

  char* ws = (char*)d_ws;
  // Workspace (~10.2 MB):
  // [0,       +64 KB)  ei
  // [65536,   +64 KB)  ej
  // [131072,  +4 KB)   blockmax (1024 floats, fully written by prep role)
  // [135168,  +2 MB)   whB (B-fragment-order Wh, 2M f16 exactly)
  // [2232320, +8 MB)   bits (2M dwords, fully written by pack role)
  float*    ei       = (float*)ws;
  float*    ej       = (float*)(ws + 65536);
  float*    blockmax = (float*)(ws + 131072);
  f16*      whB      = (f16*)(ws + 135168);
  uint32_t* bits     = (uint32_t*)(ws + 2232320);

  hipLaunchKernelGGL(gat_pp, dim3(5120), dim3(256), 0, stream,
                     h, W, a, adj, ei, ej, whB, blockmax, bits);
  hipLaunchKernelGGL(gat_attn, dim3(512), dim3(512), 0, stream,
                     bits, ei, ej, whB, blockmax, out);
}